// Round 1
// baseline (190.801 us; speedup 1.0000x reference)
//
#include <hip/hip_runtime.h>

// SpikeFP32Exp: per pixel (1024*1024), input is 32 floats in {0,1} = fp32 bit
// pattern. Reference computes shift = exp_bits - 127 (mod 256) via ripple
// adder, then emits 5-bit integer part of 1.mmmm << shift (shift in [0,4]),
// MSB-first. Collapses to: V = (s<=4) ? ((16|M) >> (4-s)) : 0.
__global__ __launch_bounds__(256) void spike_kernel(
    const float* __restrict__ x, float* __restrict__ out, int npix) {
    int p = blockIdx.x * blockDim.x + threadIdx.x;
    if (p >= npix) return;

    const float4* xb = reinterpret_cast<const float4*>(x + (size_t)p * 32);
    float4 w0 = xb[0];  // words 0..3   (word0 = sign, unused)
    float4 w1 = xb[1];  // words 4..7
    float4 w2 = xb[2];  // words 8..11
    float4 w3 = xb[3];  // words 12..15 (only word12 used)

    // Exponent bits x[...,1:9], MSB first.
    unsigned E = 0;
    E |= (unsigned)(w0.y != 0.f) << 7;
    E |= (unsigned)(w0.z != 0.f) << 6;
    E |= (unsigned)(w0.w != 0.f) << 5;
    E |= (unsigned)(w1.x != 0.f) << 4;
    E |= (unsigned)(w1.y != 0.f) << 3;
    E |= (unsigned)(w1.z != 0.f) << 2;
    E |= (unsigned)(w1.w != 0.f) << 1;
    E |= (unsigned)(w2.x != 0.f);
    // Mantissa bits x[...,9:13]: m0 (MSB of fraction) .. m3.
    unsigned M = 0;
    M |= (unsigned)(w2.y != 0.f) << 3;
    M |= (unsigned)(w2.z != 0.f) << 2;
    M |= (unsigned)(w2.w != 0.f) << 1;
    M |= (unsigned)(w3.x != 0.f);

    unsigned s = (E + 129u) & 255u;      // = (E - 127) mod 256
    unsigned u = 16u | M;                // 1.mmmm as 5-bit int
    unsigned V = (s <= 4u) ? (u >> (4u - s)) : 0u;

    float* o = out + (size_t)p * 5;
    o[0] = (float)((V >> 4) & 1u);
    o[1] = (float)((V >> 3) & 1u);
    o[2] = (float)((V >> 2) & 1u);
    o[3] = (float)((V >> 1) & 1u);
    o[4] = (float)(V & 1u);
}

extern "C" void kernel_launch(void* const* d_in, const int* in_sizes, int n_in,
                              void* d_out, int out_size, void* d_ws, size_t ws_size,
                              hipStream_t stream) {
    const float* x = (const float*)d_in[0];
    float* out = (float*)d_out;
    int npix = in_sizes[0] / 32;
    int block = 256;
    int grid = (npix + block - 1) / block;
    spike_kernel<<<grid, block, 0, stream>>>(x, out, npix);
}